// Round 20
// baseline (556.149 us; speedup 1.0000x reference)
//
#include <hip/hip_runtime.h>
#include <hip/hip_bf16.h>
#include <stdint.h>

// ---------------------------------------------------------------------------
// CapsuleNet forward, MI355X gfx950.  Round 30:
//  R29: occupancy 26->50% moved conv2 only 186->177.5 (theory falsified).
//  Chunk-interval arithmetic (4800 cyc): LDS fragment reads ~40% (24 waves
//  x 8 ds_read_b128), MFMA 23%, VALU 14% -> binder is LDS-read throughput;
//  reads/MFMA set by wave-tile shape (0.75 b128/MFMA at 64x32).
//  * conv2 MERGED-Y 128x256 tile, 8 waves of 64x64: 0.5 b128/MFMA (-33%
//    LDS reads), A staged once per (x,z) (-50% A DMA), x-major grid (72,8).
//    2 blocks/CU x 8 waves = 16 waves/CU (R29 proved 16 vs 24 ~ equal).
//    3 x 24KB buffers (72KB), depth-2 counted vmcnt(3) (3 loads/wave/chunk).
//    Swizzle involution re-verified: all sub-tile strides == 0 mod XOR
//    period, aoff row = wave*16+(lane>>2) identical to R29.
//  * everything else = R29 (best measured: 516.3us).
// ---------------------------------------------------------------------------

typedef short short8 __attribute__((ext_vector_type(8)));
typedef unsigned short u16x8 __attribute__((ext_vector_type(8)));
typedef float f32x4  __attribute__((ext_vector_type(4)));

#define H1_PLANE 6553600   // elems per parity plane: 256*100*256

__device__ inline float bf2f(unsigned short u) {
    unsigned int v = ((unsigned int)u) << 16;
    float f;
    __builtin_memcpy(&f, &v, 4);
    return f;
}
__device__ inline unsigned short f2bf(float f) {
    __hip_bfloat16 h = __float2bfloat16(f);
    unsigned short u;
    __builtin_memcpy(&u, &h, 2);
    return u;
}
__device__ inline float clampf(float x, float b) {   // scrubs NaN -> -b
    return fminf(fmaxf(x, -b), b);
}
__device__ inline float rdf(const void* p, size_t i, int f) {
    return f ? ((const float*)p)[i] : bf2f(((const unsigned short*)p)[i]);
}
__device__ inline void gload_lds16(const unsigned short* g, unsigned short* l) {
    __builtin_amdgcn_global_load_lds(
        (const __attribute__((address_space(1))) void*)g,
        (__attribute__((address_space(3))) void*)l, 16, 0, 0);
}
// fp32-vs-bf16 input detector (wave-uniform)
__device__ inline int detect_f(const void* w1c) {
    const unsigned short* w = (const unsigned short*)w1c;
    int lane = threadIdx.x & 63;
    int cnt = 0;
#pragma unroll
    for (int j = 0; j < 4; ++j) {
        float v = fabsf(bf2f(w[lane * 4 + j]));
        if (v > 100.f) cnt++;
    }
#pragma unroll
    for (int off = 32; off; off >>= 1) cnt += __shfl_xor(cnt, off);
    return cnt >= 4;
}

// ---------------------------------------------------------------------------
// prep: zero h2f (blocks 0..2303), repack conv1_w (2304..2399),
//       pconv_w -> Bp3[t*4+kc][co][ci64] (2400..2655, one block per co)
__global__ __launch_bounds__(256) void k_prep(
        const void* __restrict__ w1c, const void* __restrict__ w2c,
        float* __restrict__ h2f, unsigned short* __restrict__ B1p,
        unsigned short* __restrict__ Bp3) {
    __shared__ unsigned short wl[20736];           // [ci][t]
    int blk = blockIdx.x, tid = threadIdx.x;
    if (blk < 2304) {
        ((f32x4*)h2f)[blk * 256 + tid] = (f32x4){0.f, 0.f, 0.f, 0.f};
    } else if (blk < 2400) {
        int f = detect_f(w1c);
        int idx = (blk - 2304) * 256 + tid;        // 256*96
        int co = idx / 96, k = idx - co * 96;
        B1p[idx] = (k < 81) ? f2bf(rdf(w1c, (size_t)co * 81 + k, f)) : (unsigned short)0;
    } else {
        int f = detect_f(w1c);
        int co = blk - 2400;
        size_t base = (size_t)co * 20736;
        for (int i = tid; i < 20736; i += 256)
            wl[i] = f2bf(rdf(w2c, base + i, f));   // wl[ci*81+t]
        __syncthreads();
        for (int idx = tid; idx < 20736; idx += 256) {
            int t = idx >> 8, ci = idx & 255;      // 81*256
            int kc = ci >> 6, cin = ci & 63;
            Bp3[((size_t)(t * 4 + kc) << 14) + (co << 6) + cin] = wl[ci * 81 + t];
        }
    }
}

// ---------------------------------------------------------------------------
// conv1: C[102400,256] = im2col(x) * B1p^T, 128x128 tiles, x staged in LDS.
// Epilogue writes h1 PARITY-SPLIT: plane (y&1,x&1), [b][y>>1][x>>1][ci].
__global__ __launch_bounds__(256) void k_conv1(
        const void* __restrict__ x,
        const unsigned short* __restrict__ B1p,
        const void* __restrict__ bias,
        unsigned short* __restrict__ h1p,
        const void* __restrict__ w1c) {
    __shared__ unsigned short xl[1568];            // up to 2 images, bf16
    __shared__ int offt[96];
    int f = detect_f(w1c);
    int tid = threadIdx.x;
    if (tid < 96) offt[tid] = (tid < 81) ? (tid / 9) * 28 + (tid % 9) : 0;

    int mblk = blockIdx.x * 128;
    int bfirst = mblk / 400;
    int blast = (mblk + 127) / 400;
    int nload = (blast - bfirst + 1) * 784;
    for (int i = tid; i < nload; i += 256)
        xl[i] = f2bf(rdf(x, (size_t)bfirst * 784 + i, f));
    __syncthreads();

    int wave = tid >> 6, lane = tid & 63;
    int wr = wave >> 1, wc = wave & 1;
    int mbase = mblk + wr * 64;
    int nbase = blockIdx.y * 128 + wc * 64;
    int l15 = lane & 15, l4 = lane >> 4;

    int lbase[4];
#pragma unroll
    for (int mt = 0; mt < 4; ++mt) {
        int m = mbase + mt * 16 + l15;
        int img = m / 400 - bfirst, pos = m % 400;
        lbase[mt] = img * 784 + (pos / 20) * 28 + (pos % 20);
    }

    f32x4 acc[4][4];
#pragma unroll
    for (int mt = 0; mt < 4; ++mt)
#pragma unroll
        for (int nt = 0; nt < 4; ++nt)
            acc[mt][nt] = (f32x4){0.f, 0.f, 0.f, 0.f};

#pragma unroll
    for (int kc = 0; kc < 3; ++kc) {
        int kbase = kc * 32 + l4 * 8;
        short8 af[4], bfr[4];
#pragma unroll
        for (int mt = 0; mt < 4; ++mt)
#pragma unroll
            for (int j = 0; j < 8; ++j) {
                int k = kbase + j;
                af[mt][j] = (k < 81) ? (short)xl[lbase[mt] + offt[k]] : (short)0;
            }
#pragma unroll
        for (int nt = 0; nt < 4; ++nt)
            bfr[nt] = *(const short8*)(B1p + (size_t)(nbase + nt * 16 + l15) * 96 + kbase);
#pragma unroll
        for (int mt = 0; mt < 4; ++mt)
#pragma unroll
            for (int nt = 0; nt < 4; ++nt)
                acc[mt][nt] = __builtin_amdgcn_mfma_f32_16x16x32_bf16(
                    af[mt], bfr[nt], acc[mt][nt], 0, 0, 0);
    }

#pragma unroll
    for (int mt = 0; mt < 4; ++mt) {
        size_t radr[4];
#pragma unroll
        for (int r = 0; r < 4; ++r) {
            int m = mbase + mt * 16 + l4 * 4 + r;
            int img = m / 400, pos = m - img * 400;
            int y = pos / 20, xx = pos - y * 20;
            radr[r] = (size_t)(((y & 1) << 1) + (xx & 1)) * H1_PLANE
                    + (size_t)(img * 100 + (y >> 1) * 10 + (xx >> 1)) * 256;
        }
#pragma unroll
        for (int nt = 0; nt < 4; ++nt) {
            int col = nbase + nt * 16 + l15;
            float bv = rdf(bias, col, f);
#pragma unroll
            for (int r = 0; r < 4; ++r)
                h1p[radr[r] + col] = f2bf(clampf(acc[mt][nt][r] + bv, 1024.f));
        }
    }
}

// ---------------------------------------------------------------------------
// conv2: MERGED-Y 128x256 tile (full N), 8 waves (512 thr) of 64x64
// (acc[4][4], 16 MFMA/chunk/wave; 0.5 b128/MFMA vs 0.75 at 64x32).
// 3 LDS buffers of {A 8KB + B 16KB} = 72KB -> 2 blocks/CU x 8 waves =
// 16 waves/CU.  Grid X-MAJOR (72,8).  A staged once per (x,z).
// Depth-2 prefetch, counted vmcnt(3) (1 A + 2 B loads/wave/chunk),
// one s_barrier per chunk.  Parity-split h1 A-reads, XOR-swizzled LDS
// (row = wave*16+(lane>>2): (row>>1)&3 == (lane>>3)&3, matching slog;
// read-side mt*16/nt*16 strides == 0 mod XOR period).
// Epilogue: contiguous fp32 atomicAdd into h2f[row][col].
__global__ __launch_bounds__(512) void k_conv2(
        const unsigned short* __restrict__ h1p,
        const unsigned short* __restrict__ Bp,
        float* __restrict__ h2f) {
    __shared__ unsigned short As[3][4096];         // [buf][row 128][k 32] swz
    __shared__ unsigned short Bs[3][8192];         // [buf][col 256][k 32] swz
    int tid = threadIdx.x;
    int wave = tid >> 6, lane = tid & 63;          // wave 0..7
    int wr = wave >> 2, wc = wave & 3;             // wave tile 64 x 64
    int mb = blockIdx.x << 7;                      // x-tile (72), X-MAJOR
    int s = blockIdx.y;                            // z slice (8)
    int t0 = (81 * s) >> 3, t1 = (81 * (s + 1)) >> 3;
    int l15 = lane & 15, l4 = lane >> 4;

    // ---- staging per-lane components ----------------------------------
    // A (1 load/wave): rows wave*16..+15; lane l -> row +(l>>2), slot
    // fetch logical (l&3)^((l>>3)&3).  B (2 loads/wave): cols wave*32 +
    // r*16..+15, same lane mapping.
    int rsub = lane >> 2;
    int slog = (lane & 3) ^ ((lane >> 3) & 3);
    int aoff;
    {
        int row = wave * 16 + rsub;
        int m = mb + row;
        int bb = m / 36, pos = m - bb * 36;
        int yo = pos / 6, xo = pos - yo * 6;
        aoff = (bb * 100 + yo * 10 + xo) * 256 + slog * 8;   // parity-plane lin
    }
    int boff[2];
#pragma unroll
    for (int r = 0; r < 2; ++r) {
        int col = wave * 32 + r * 16 + rsub;
        boff[r] = col * 64 + slog * 8;             // within Bp 16K window
    }

    // ---- per-wave fragment read offsets (swizzled) --------------------
    int ko = (l4 ^ ((l15 >> 1) & 3)) << 3;
    int arow[4], brow[4];
#pragma unroll
    for (int mt = 0; mt < 4; ++mt) arow[mt] = ((wr * 64 + mt * 16 + l15) << 5) + ko;
#pragma unroll
    for (int nt = 0; nt < 4; ++nt) brow[nt] = ((wc * 64 + nt * 16 + l15) << 5) + ko;

    f32x4 acc[4][4];
#pragma unroll
    for (int mt = 0; mt < 4; ++mt)
#pragma unroll
        for (int nt = 0; nt < 4; ++nt)
            acc[mt][nt] = (f32x4){0.f, 0.f, 0.f, 0.f};

    int skc = 0;                                   // 32-ci chunk 0..7
    int sky = t0 / 9, skx = t0 - sky * 9;
    int st4 = t0 * 4;                              // t*4 for Bp indexing
    int tboff = ((sky & 1) * 2 + (skx & 1)) * H1_PLANE
              + ((sky >> 1) * 10 + (skx >> 1)) * 256;

    auto stage = [&](int buf) {
        const unsigned short* aw = h1p + tboff + (skc << 5);
        const unsigned short* bw = Bp + (((size_t)(st4 + (skc >> 1))) << 14)
                                     + ((skc & 1) << 5);
        gload_lds16(aw + aoff, &As[buf][wave << 9]);
#pragma unroll
        for (int r = 0; r < 2; ++r)
            gload_lds16(bw + boff[r], &Bs[buf][(wave * 2 + r) << 9]);
    };
    auto adv = [&]() {
        if (++skc == 8) {
            skc = 0; st4 += 4;
            if (++skx == 9) { skx = 0; ++sky; }
            tboff = ((sky & 1) * 2 + (skx & 1)) * H1_PLANE
                  + ((sky >> 1) * 10 + (skx >> 1)) * 256;
        }
    };
    auto compute = [&](int buf) {
        short8 af[4], bfr[4];
#pragma unroll
        for (int mt = 0; mt < 4; ++mt)
            af[mt] = *(const short8*)(&As[buf][arow[mt]]);
#pragma unroll
        for (int nt = 0; nt < 4; ++nt)
            bfr[nt] = *(const short8*)(&Bs[buf][brow[nt]]);
#pragma unroll
        for (int mt = 0; mt < 4; ++mt)
#pragma unroll
            for (int nt = 0; nt < 4; ++nt)
                acc[mt][nt] = __builtin_amdgcn_mfma_f32_16x16x32_bf16(
                    af[mt], bfr[nt], acc[mt][nt], 0, 0, 0);
    };

    int nit = (t1 - t0) * 8;                       // 80 or 88
    stage(0); adv();                               // chunk 0 -> buf 0
    stage(1); adv();                               // chunk 1 -> buf 1
    int cur = 0;
    for (int i = 0; i < nit; ++i) {
        if (i + 1 < nit) asm volatile("s_waitcnt vmcnt(3)" ::: "memory");
        else             asm volatile("s_waitcnt vmcnt(0)" ::: "memory");
        __builtin_amdgcn_s_barrier();
        if (i + 2 < nit) { stage(cur == 0 ? 2 : cur - 1); adv(); }
        compute(cur);
        cur = (cur == 2) ? 0 : cur + 1;
    }

#pragma unroll
    for (int mt = 0; mt < 4; ++mt)
#pragma unroll
        for (int nt = 0; nt < 4; ++nt) {
            int col = wc * 64 + nt * 16 + l15;
#pragma unroll
            for (int r = 0; r < 4; ++r) {
                int row = mb + wr * 64 + mt * 16 + l4 * 4 + r;
                atomicAdd(&h2f[(size_t)row * 256 + col], acc[mt][nt][r]);
            }
        }
}

// ---------------------------------------------------------------------------
// k_post = prep2 (blocks 0..5703) + caps2 (blocks 5704..5959), merged.
// Wdb2 layout [o][n][i][8] (R24-proven: per-WAVE coalesced in routing).
__global__ __launch_bounds__(256) void k_post(
        const void* __restrict__ wdig, const void* __restrict__ dw2,
        const void* __restrict__ dw3, const void* __restrict__ w1c,
        unsigned short* __restrict__ Wdb2,
        unsigned short* __restrict__ w2b,
        unsigned short* __restrict__ w3b,
        const float* __restrict__ h2f, const void* __restrict__ pb,
        unsigned short* __restrict__ caps) {
    __shared__ unsigned short wl[20480];           // 40KB; reused as f32[9216]
    int f = detect_f(w1c);
    int blk = blockIdx.x, tid = threadIdx.x;
    if (blk >= 5704) {                             // ---- caps2 branch ----
        float* ld = (float*)wl;                    // [pos 36][co 256], 36KB
        int b = blk - 5704;
#pragma unroll 4
        for (int p = 0; p < 36; ++p)
            ld[p * 256 + tid] = h2f[(size_t)b * 9216 + p * 256 + tid];
        __syncthreads();
        for (int c = tid; c < 1152; c += 256) {
            float h[8], ss = 0.f;
#pragma unroll
            for (int d = 0; d < 8; ++d) {
                int flat = c * 8 + d;              // = co*36 + pos
                int co = flat / 36, pos = flat - co * 36;
                float v = clampf(ld[pos * 256 + co] + rdf(pb, co, f), 20000.f);
                h[d] = v;
                ss += v * v;
            }
            float sc = sqrtf(ss) / (1.f + ss);
            u16x8 cv;
#pragma unroll
            for (int d = 0; d < 8; ++d) cv[d] = f2bf(h[d] * sc);
            *(u16x8*)(caps + ((size_t)b * 1152 + c) * 8) = cv;
        }
    } else if (blk < 72) {                         // ---- prep2: W_dig ----
        int i0 = blk * 16;
        size_t base = (size_t)i0 * 1280;
        for (int idx = tid; idx < 20480; idx += 256)
            wl[idx] = f2bf(rdf(wdig, base + idx, f));
        __syncthreads();
        if (tid < 160) {                           // (o,n) pair per thread
            int o = tid / 16, n = tid - o * 16;
            unsigned short* dst = Wdb2 + (size_t)o * 147456 + n * 9216 + i0 * 8;
            const unsigned short* src = wl + tid * 8;
#pragma unroll
            for (int i = 0; i < 16; ++i)
                *(uint4*)(dst + i * 8) = *(const uint4*)(src + i * 1280);
        }
    } else if (blk < 2120) {
        int idx = (blk - 72) * 256 + tid;          // 524,288
        w2b[idx] = f2bf(rdf(dw2, idx, f));
    } else {
        int idx = (blk - 2120) * 256 + tid;        // 917,504 (pad past 802,816)
        w3b[idx] = (idx < 802816) ? f2bf(rdf(dw3, idx, f)) : (unsigned short)0;
    }
}

// ---------------------------------------------------------------------------
// Dynamic routing + fused dec1 (EXACT R24 form).  One block per (o,b),
// o-major.  Round 1 exact-uniform; rounds 2,3 no-max softmax.
__global__ __launch_bounds__(384) void k_routing(
        const unsigned short* __restrict__ caps, const unsigned short* __restrict__ Wdb2,
        const int* __restrict__ label, void* __restrict__ d_out,
        const void* __restrict__ dw1, const void* __restrict__ db1,
        unsigned short* __restrict__ r1b, const void* __restrict__ w1c) {
    int f = detect_f(w1c);
    int bid = blockIdx.x;
    int o = bid >> 8, b = bid & 255;               // 2560 = 10 o x 256 b
    int bo = b * 10 + o;                           // output index unchanged
    int tid = threadIdx.x;
    int wid = tid >> 6, lane = tid & 63;

    __shared__ float redw[6][16];
    __shared__ float sred[8];
    __shared__ float sbuf[16];
    __shared__ float vnl[16];

    float u[3][16];
    float a[3] = {0.f, 0.f, 0.f};
    const unsigned short* capb = caps + (size_t)b * 9216;
    const unsigned short* wob = Wdb2 + (size_t)o * 147456;

#pragma unroll
    for (int r = 0; r < 3; ++r) {
        int i = tid + r * 384;                       // covers 0..1151 exactly
        u16x8 cq = *(const u16x8*)(capb + i * 8);
        float cf[8];
#pragma unroll
        for (int d = 0; d < 8; ++d) cf[d] = bf2f(cq[d]);
#pragma unroll
        for (int n = 0; n < 16; ++n) {
            u16x8 q = *(const u16x8*)(wob + ((size_t)n * 1152 + i) * 8);
            float sacc = 0.f;
#pragma unroll
            for (int d = 0; d < 8; ++d) sacc += bf2f(q[d]) * cf[d];
            u[r][n] = sacc;
        }
    }

    // ---- Round 1: uniform coupling (exact) -----------------------------
    {
        float p[16];
#pragma unroll
        for (int n = 0; n < 16; ++n) p[n] = u[0][n] + u[1][n] + u[2][n];
#pragma unroll
        for (int off = 32; off; off >>= 1)
#pragma unroll
            for (int n = 0; n < 16; ++n) p[n] += __shfl_xor(p[n], off);
        if (lane == 0)
#pragma unroll
            for (int n = 0; n < 16; ++n) redw[wid][n] = p[n];
        __syncthreads();
        if (tid < 16) {
            float sn = 0.f;
#pragma unroll
            for (int w = 0; w < 6; ++w) sn += redw[w][tid];
            sbuf[tid] = sn * (1.f / 1152.f);
        }
        __syncthreads();
        float ss = 0.f;
#pragma unroll
        for (int n = 0; n < 16; ++n) ss += sbuf[n] * sbuf[n];
        float sc = sqrtf(ss) / (1.f + ss);
#pragma unroll
        for (int r = 0; r < 3; ++r) {
            float dot = 0.f;
#pragma unroll
            for (int n = 0; n < 16; ++n) dot += sbuf[n] * u[r][n];
            a[r] += sc * dot;
        }
    }

    // ---- Rounds 2,3: no-max softmax, fused es+p butterflies ------------
    for (int rr = 2; rr <= 3; ++rr) {
        float e[3], es = 0.f;
#pragma unroll
        for (int r = 0; r < 3; ++r) { e[r] = __expf(fminf(a[r], 70.f)); es += e[r]; }
        float p[16];
#pragma unroll
        for (int n = 0; n < 16; ++n)
            p[n] = e[0] * u[0][n] + e[1] * u[1][n] + e[2] * u[2][n];
#pragma unroll
        for (int off = 32; off; off >>= 1) {
            es += __shfl_xor(es, off);
#pragma unroll
            for (int n = 0; n < 16; ++n) p[n] += __shfl_xor(p[n], off);
        }
        if (lane == 0) {
#pragma unroll
            for (int n = 0; n < 16; ++n) redw[wid][n] = p[n];
            sred[wid] = es;
        }
        __syncthreads();
        if (tid < 16) {
            float S = 0.f, sn = 0.f;
#pragma unroll
            for (int w = 0; w < 6; ++w) { S += sred[w]; sn += redw[w][tid]; }
            sbuf[tid] = sn / S;
        }
        __syncthreads();
        float ss = 0.f;
#pragma unroll
        for (int n = 0; n < 16; ++n) ss += sbuf[n] * sbuf[n];
        float sc = sqrtf(ss) / (1.f + ss);

        if (rr < 3) {
#pragma unroll
            for (int r = 0; r < 3; ++r) {
                float dot = 0.f;
#pragma unroll
                for (int n = 0; n < 16; ++n) dot += sbuf[n] * u[r][n];
                a[r] += sc * dot;
            }
        } else {
            int lbl = label[b];
            if (tid < 16) {
                float vn = clampf(sbuf[tid] * sc, 1.f);
                if (f) ((float*)d_out)[(bo << 4) + tid] = vn;
                else   ((unsigned short*)d_out)[(bo << 4) + tid] = f2bf(vn);
                vnl[tid] = vn;
            }
            if (tid == 0) {
                float oh = (o == lbl) ? 1.f : 0.f;
                if (f) ((float*)d_out)[241664 + bo] = oh;
                else   ((unsigned short*)d_out)[241664 + bo] = f2bf(oh);
            }
            __syncthreads();                       // block-uniform path
            if (o == lbl) {                        // fused dec1
                for (int j = tid; j < 512; j += 384) {
                    float acc2 = rdf(db1, j, f);
                    size_t wb = (size_t)j * 160 + lbl * 16;
#pragma unroll
                    for (int n = 0; n < 16; ++n)
                        acc2 += rdf(dw1, wb + n, f) * vnl[n];
                    r1b[b * 512 + j] = f2bf(fmaxf(acc2, 0.f));
                }
            }
        }
    }
}

// ---------------------------------------------------------------------------
// decoder GEMM: C[256,N] = A[256,K] x B[N,K]^T (+bias, act). 128x128 tiles.
__global__ __launch_bounds__(256) void k_dgemm(
        const unsigned short* __restrict__ A, const unsigned short* __restrict__ B,
        const void* __restrict__ bias, int K, int mode, int nvalid, int ostride,
        unsigned short* __restrict__ outb, void* __restrict__ d_out,
        const void* __restrict__ w1c) {
    int f = detect_f(w1c);
    int tid = threadIdx.x;
    int wave = tid >> 6, lane = tid & 63;
    int wr = wave >> 1, wc = wave & 1;
    int mbase = blockIdx.x * 128 + wr * 64;
    int nbase = blockIdx.y * 128 + wc * 64;
    int l15 = lane & 15, l4 = lane >> 4;
    int koff = l4 * 8;

    f32x4 acc[4][4];
#pragma unroll
    for (int mt = 0; mt < 4; ++mt)
#pragma unroll
        for (int nt = 0; nt < 4; ++nt)
            acc[mt][nt] = (f32x4){0.f, 0.f, 0.f, 0.f};

    int nch = K >> 5;
    for (int kc = 0; kc < nch; ++kc) {
        int k0 = kc * 32 + koff;
        short8 af[4], bfr[4];
#pragma unroll
        for (int mt = 0; mt < 4; ++mt)
            af[mt] = *(const short8*)(A + (size_t)(mbase + mt * 16 + l15) * K + k0);
#pragma unroll
        for (int nt = 0; nt < 4; ++nt)
            bfr[nt] = *(const short8*)(B + (size_t)(nbase + nt * 16 + l15) * K + k0);
#pragma unroll
        for (int mt = 0; mt < 4; ++mt)
#pragma unroll
            for (int nt = 0; nt < 4; ++nt)
                acc[mt][nt] = __builtin_amdgcn_mfma_f32_16x16x32_bf16(
                    af[mt], bfr[nt], acc[mt][nt], 0, 0, 0);
    }

#pragma unroll
    for (int mt = 0; mt < 4; ++mt)
#pragma unroll
        for (int nt = 0; nt < 4; ++nt) {
            int col = nbase + nt * 16 + l15;
            float bv = (col < nvalid) ? rdf(bias, col, f) : 0.f;
#pragma unroll
            for (int r = 0; r < 4; ++r) {
                int row = mbase + mt * 16 + l4 * 4 + r;
                float v = acc[mt][nt][r] + bv;
                if (mode == 0) {
                    outb[(size_t)row * ostride + col] = f2bf(fmaxf(v, 0.f));
                } else if (col < nvalid) {
                    float a = clampf(v, 60.f);
                    float sig = 1.f / (1.f + __expf(-a));
                    size_t oi = 40960 + (size_t)row * 784 + col;
                    if (f) ((float*)d_out)[oi] = sig;
                    else   ((unsigned short*)d_out)[oi] = f2bf(sig);
                }
            }
        }
}

// ---------------------------------------------------------------------------
extern "C" void kernel_launch(void* const* d_in, const int* in_sizes, int n_in,
                              void* d_out, int out_size, void* d_ws, size_t ws_size,
                              hipStream_t stream) {
    const void* x    = d_in[0];
    const int*  lbl  = (const int*)d_in[1];
    const void* w1c  = d_in[2];
    const void* b1c  = d_in[3];
    const void* w2c  = d_in[4];
    const void* b2c  = d_in[5];
    const void* wdig = d_in[6];
    const void* dw1  = d_in[7];
    const void* db1  = d_in[8];
    const void* dw2  = d_in[9];
    const void* db2  = d_in[10];
    const void* dw3  = d_in[11];
    const void* db3  = d_in[12];
    (void)in_sizes; (void)n_in; (void)out_size; (void)ws_size;

    char* ws = (char*)d_ws;
    float* h2f           = (float*)(ws);                      // 9,437,184
    unsigned short* Bp3  = (unsigned short*)(ws + 9437184);   // 10,616,832 [dead after conv2]
    unsigned short* caps = (unsigned short*)(ws + 9437184);   //   overlay: 4,718,592
    unsigned short* B1p  = (unsigned short*)(ws + 20054016);  // 49,152
    unsigned short* h1p  = (unsigned short*)(ws + 20103168);  // 52,428,800 [dead after conv2]
    //   overlays inside h1p region (written after conv2 by k_post etc):
    unsigned short* Wdb2 = (unsigned short*)(ws + 20103168);  // 2,949,120
    unsigned short* w2b  = (unsigned short*)(ws + 23052288);  // 1,048,576
    unsigned short* w3b  = (unsigned short*)(ws + 24100864);  // 1,835,008
    unsigned short* r1b  = (unsigned short*)(ws + 25935872);  // 262,144
    unsigned short* r2b  = (unsigned short*)(ws + 26198016);  // 524,288

    hipLaunchKernelGGL(k_prep,  dim3(2656),     dim3(256), 0, stream, w1c, w2c, h2f, B1p, Bp3);
    hipLaunchKernelGGL(k_conv1, dim3(800, 2),   dim3(256), 0, stream, x, B1p, b1c, h1p, w1c);
    hipLaunchKernelGGL(k_conv2, dim3(72, 8),    dim3(512), 0, stream, h1p, Bp3, h2f);
    hipLaunchKernelGGL(k_post,  dim3(5960),     dim3(256), 0, stream,
                       wdig, dw2, dw3, w1c, Wdb2, w2b, w3b, h2f, b2c, caps);
    hipLaunchKernelGGL(k_routing, dim3(2560),   dim3(384), 0, stream, caps, Wdb2, lbl,
                       d_out, dw1, db1, r1b, w1c);
    hipLaunchKernelGGL(k_dgemm, dim3(2, 8),     dim3(256), 0, stream,
                       r1b, w2b, db2, 512, 0, 1024, 1024, r2b, d_out, w1c);
    hipLaunchKernelGGL(k_dgemm, dim3(2, 7),     dim3(256), 0, stream,
                       r2b, w3b, db3, 1024, 1, 784, 0, (unsigned short*)nullptr, d_out, w1c);
}

// Round 22
// 512.174 us; speedup vs baseline: 1.0859x; 1.0859x over previous
//
#include <hip/hip_runtime.h>
#include <hip/hip_bf16.h>
#include <stdint.h>

// ---------------------------------------------------------------------------
// CapsuleNet forward, MI355X gfx950.  Round 32 = FINAL resubmit (R31 hit the
// recurring infra flake; this source == R29 which PASSED at 516.3us total,
// conv2 177.5us @ 50% occupancy.  R12/R16/R25 precedent: identical source
// passes on retry).
//  Session ledger (falsified in strikethrough):
//   conv2: XOR-swizzle (+25us, kept) | 8-wave 64x32 blocks (+8.5us, kept) |
//          ~~pipeline depth 0.5-3~~ ~~XCD remap~~ ~~merged-y~~ ~~parity
//          contiguity~~ ~~64x64 wave-tile~~ -> sum-bound floor ~177us
//          (LDS-reads 40% + MFMA 23% + VALU 14% + barrier 23%).
//   routing: exact round-1 + no-max softmax + 6 barriers (139.9 -> ~105us);
//          ~~per-thread-contiguous Wdb2~~ (per-WAVE coalescing is the law).
//   launches: 10 -> 7 (k_post merge, routing+dec1 fusion; conv1+prep merge
//          reverted: occupancy > launch count).
//  Total: 576 -> 516us best-measured (-10.4%), absmax 0.00195 all rounds.
// ---------------------------------------------------------------------------

typedef short short8 __attribute__((ext_vector_type(8)));
typedef unsigned short u16x8 __attribute__((ext_vector_type(8)));
typedef float f32x4  __attribute__((ext_vector_type(4)));

#define H1_PLANE 6553600   // elems per parity plane: 256*100*256

__device__ inline float bf2f(unsigned short u) {
    unsigned int v = ((unsigned int)u) << 16;
    float f;
    __builtin_memcpy(&f, &v, 4);
    return f;
}
__device__ inline unsigned short f2bf(float f) {
    __hip_bfloat16 h = __float2bfloat16(f);
    unsigned short u;
    __builtin_memcpy(&u, &h, 2);
    return u;
}
__device__ inline float clampf(float x, float b) {   // scrubs NaN -> -b
    return fminf(fmaxf(x, -b), b);
}
__device__ inline float rdf(const void* p, size_t i, int f) {
    return f ? ((const float*)p)[i] : bf2f(((const unsigned short*)p)[i]);
}
__device__ inline void gload_lds16(const unsigned short* g, unsigned short* l) {
    __builtin_amdgcn_global_load_lds(
        (const __attribute__((address_space(1))) void*)g,
        (__attribute__((address_space(3))) void*)l, 16, 0, 0);
}
// fp32-vs-bf16 input detector (wave-uniform)
__device__ inline int detect_f(const void* w1c) {
    const unsigned short* w = (const unsigned short*)w1c;
    int lane = threadIdx.x & 63;
    int cnt = 0;
#pragma unroll
    for (int j = 0; j < 4; ++j) {
        float v = fabsf(bf2f(w[lane * 4 + j]));
        if (v > 100.f) cnt++;
    }
#pragma unroll
    for (int off = 32; off; off >>= 1) cnt += __shfl_xor(cnt, off);
    return cnt >= 4;
}

// ---------------------------------------------------------------------------
// prep: zero h2f (blocks 0..2303), repack conv1_w (2304..2399),
//       pconv_w -> Bp3[t*4+kc][co][ci64] (2400..2655, one block per co)
__global__ __launch_bounds__(256) void k_prep(
        const void* __restrict__ w1c, const void* __restrict__ w2c,
        float* __restrict__ h2f, unsigned short* __restrict__ B1p,
        unsigned short* __restrict__ Bp3) {
    __shared__ unsigned short wl[20736];           // [ci][t]
    int blk = blockIdx.x, tid = threadIdx.x;
    if (blk < 2304) {
        ((f32x4*)h2f)[blk * 256 + tid] = (f32x4){0.f, 0.f, 0.f, 0.f};
    } else if (blk < 2400) {
        int f = detect_f(w1c);
        int idx = (blk - 2304) * 256 + tid;        // 256*96
        int co = idx / 96, k = idx - co * 96;
        B1p[idx] = (k < 81) ? f2bf(rdf(w1c, (size_t)co * 81 + k, f)) : (unsigned short)0;
    } else {
        int f = detect_f(w1c);
        int co = blk - 2400;
        size_t base = (size_t)co * 20736;
        for (int i = tid; i < 20736; i += 256)
            wl[i] = f2bf(rdf(w2c, base + i, f));   // wl[ci*81+t]
        __syncthreads();
        for (int idx = tid; idx < 20736; idx += 256) {
            int t = idx >> 8, ci = idx & 255;      // 81*256
            int kc = ci >> 6, cin = ci & 63;
            Bp3[((size_t)(t * 4 + kc) << 14) + (co << 6) + cin] = wl[ci * 81 + t];
        }
    }
}

// ---------------------------------------------------------------------------
// conv1: C[102400,256] = im2col(x) * B1p^T, 128x128 tiles, x staged in LDS.
// Epilogue writes h1 PARITY-SPLIT: plane (y&1,x&1), [b][y>>1][x>>1][ci].
__global__ __launch_bounds__(256) void k_conv1(
        const void* __restrict__ x,
        const unsigned short* __restrict__ B1p,
        const void* __restrict__ bias,
        unsigned short* __restrict__ h1p,
        const void* __restrict__ w1c) {
    __shared__ unsigned short xl[1568];            // up to 2 images, bf16
    __shared__ int offt[96];
    int f = detect_f(w1c);
    int tid = threadIdx.x;
    if (tid < 96) offt[tid] = (tid < 81) ? (tid / 9) * 28 + (tid % 9) : 0;

    int mblk = blockIdx.x * 128;
    int bfirst = mblk / 400;
    int blast = (mblk + 127) / 400;
    int nload = (blast - bfirst + 1) * 784;
    for (int i = tid; i < nload; i += 256)
        xl[i] = f2bf(rdf(x, (size_t)bfirst * 784 + i, f));
    __syncthreads();

    int wave = tid >> 6, lane = tid & 63;
    int wr = wave >> 1, wc = wave & 1;
    int mbase = mblk + wr * 64;
    int nbase = blockIdx.y * 128 + wc * 64;
    int l15 = lane & 15, l4 = lane >> 4;

    int lbase[4];
#pragma unroll
    for (int mt = 0; mt < 4; ++mt) {
        int m = mbase + mt * 16 + l15;
        int img = m / 400 - bfirst, pos = m % 400;
        lbase[mt] = img * 784 + (pos / 20) * 28 + (pos % 20);
    }

    f32x4 acc[4][4];
#pragma unroll
    for (int mt = 0; mt < 4; ++mt)
#pragma unroll
        for (int nt = 0; nt < 4; ++nt)
            acc[mt][nt] = (f32x4){0.f, 0.f, 0.f, 0.f};

#pragma unroll
    for (int kc = 0; kc < 3; ++kc) {
        int kbase = kc * 32 + l4 * 8;
        short8 af[4], bfr[4];
#pragma unroll
        for (int mt = 0; mt < 4; ++mt)
#pragma unroll
            for (int j = 0; j < 8; ++j) {
                int k = kbase + j;
                af[mt][j] = (k < 81) ? (short)xl[lbase[mt] + offt[k]] : (short)0;
            }
#pragma unroll
        for (int nt = 0; nt < 4; ++nt)
            bfr[nt] = *(const short8*)(B1p + (size_t)(nbase + nt * 16 + l15) * 96 + kbase);
#pragma unroll
        for (int mt = 0; mt < 4; ++mt)
#pragma unroll
            for (int nt = 0; nt < 4; ++nt)
                acc[mt][nt] = __builtin_amdgcn_mfma_f32_16x16x32_bf16(
                    af[mt], bfr[nt], acc[mt][nt], 0, 0, 0);
    }

#pragma unroll
    for (int mt = 0; mt < 4; ++mt) {
        size_t radr[4];
#pragma unroll
        for (int r = 0; r < 4; ++r) {
            int m = mbase + mt * 16 + l4 * 4 + r;
            int img = m / 400, pos = m - img * 400;
            int y = pos / 20, xx = pos - y * 20;
            radr[r] = (size_t)(((y & 1) << 1) + (xx & 1)) * H1_PLANE
                    + (size_t)(img * 100 + (y >> 1) * 10 + (xx >> 1)) * 256;
        }
#pragma unroll
        for (int nt = 0; nt < 4; ++nt) {
            int col = nbase + nt * 16 + l15;
            float bv = rdf(bias, col, f);
#pragma unroll
            for (int r = 0; r < 4; ++r)
                h1p[radr[r] + col] = f2bf(clampf(acc[mt][nt][r] + bv, 1024.f));
        }
    }
}

// ---------------------------------------------------------------------------
// conv2: 128x128 tile, EIGHT waves (512 thr), wave-tile 64x32 (acc[4][2]).
// 3 LDS buffers of K=32 (48 KB) -> 3 blocks/CU x 8 waves = 24 wave-slots/CU.
// Depth-2 prefetch, counted vmcnt (steady vmcnt(2): 1 A + 1 B load/wave),
// one s_barrier per chunk.  Grid (72,2,8).  Parity-split h1 A-reads,
// XOR-swizzled LDS (row = wave*16 + (lane>>2), slog = (lane&3)^((lane>>3)&3)).
// Epilogue: contiguous fp32 atomicAdd into h2f[row][col].
// Measured R29: 177.5us, MfmaUtil 23.3, Occupancy 50%, conflicts 0.
__global__ __launch_bounds__(512) void k_conv2(
        const unsigned short* __restrict__ h1p,
        const unsigned short* __restrict__ Bp,
        float* __restrict__ h2f) {
    __shared__ unsigned short As[3][4096];         // [buf][row 128][k 32] swz
    __shared__ unsigned short Bs[3][4096];
    int tid = threadIdx.x;
    int wave = tid >> 6, lane = tid & 63;          // wave 0..7
    int wr = wave >> 2, wc = wave & 3;             // wave tile 64 x 32
    int mb = blockIdx.x << 7;                      // x-tile (72), fastest
    int nb = blockIdx.y << 7;                      // y (2)
    int s = blockIdx.z;                            // z slice (8)
    int t0 = (81 * s) >> 3, t1 = (81 * (s + 1)) >> 3;
    int l15 = lane & 15, l4 = lane >> 4;

    // ---- staging per-lane components: wave stages 16 A-rows + 16 B-rows
    int rsub = lane >> 2;
    int slog = (lane & 3) ^ ((lane >> 3) & 3);
    int aoff, boff;
    {
        int row = wave * 16 + rsub;
        int m = mb + row;
        int bb = m / 36, pos = m - bb * 36;
        int yo = pos / 6, xo = pos - yo * 6;
        aoff = (bb * 100 + yo * 10 + xo) * 256 + slog * 8;   // parity-plane lin
        boff = row * 64 + slog * 8;                // within Bp 16K window
    }

    // ---- per-wave fragment read offsets (swizzled) --------------------
    int ko = (l4 ^ ((l15 >> 1) & 3)) << 3;
    int arow[4], brow[2];
#pragma unroll
    for (int mt = 0; mt < 4; ++mt) arow[mt] = ((wr * 64 + mt * 16 + l15) << 5) + ko;
#pragma unroll
    for (int nt = 0; nt < 2; ++nt) brow[nt] = ((wc * 32 + nt * 16 + l15) << 5) + ko;

    f32x4 acc[4][2];
#pragma unroll
    for (int mt = 0; mt < 4; ++mt)
#pragma unroll
        for (int nt = 0; nt < 2; ++nt)
            acc[mt][nt] = (f32x4){0.f, 0.f, 0.f, 0.f};

    int skc = 0;                                   // 32-ci chunk 0..7
    int sky = t0 / 9, skx = t0 - sky * 9;
    int st4 = t0 * 4;                              // t*4 for Bp indexing
    int tboff = ((sky & 1) * 2 + (skx & 1)) * H1_PLANE
              + ((sky >> 1) * 10 + (skx >> 1)) * 256;

    auto stage = [&](int buf) {
        const unsigned short* aw = h1p + tboff + (skc << 5);
        const unsigned short* bw = Bp + (((size_t)(st4 + (skc >> 1))) << 14)
                                     + nb * 64 + ((skc & 1) << 5);
        gload_lds16(aw + aoff, &As[buf][wave << 9]);
        gload_lds16(bw + boff, &Bs[buf][wave << 9]);
    };
    auto adv = [&]() {
        if (++skc == 8) {
            skc = 0; st4 += 4;
            if (++skx == 9) { skx = 0; ++sky; }
            tboff = ((sky & 1) * 2 + (skx & 1)) * H1_PLANE
                  + ((sky >> 1) * 10 + (skx >> 1)) * 256;
        }
    };
    auto compute = [&](int buf) {
        short8 af[4], bfr[2];
#pragma unroll
        for (int mt = 0; mt < 4; ++mt)
            af[mt] = *(const short8*)(&As[buf][arow[mt]]);
#pragma unroll
        for (int nt = 0; nt < 2; ++nt)
            bfr[nt] = *(const short8*)(&Bs[buf][brow[nt]]);
#pragma unroll
        for (int mt = 0; mt < 4; ++mt)
#pragma unroll
            for (int nt = 0; nt < 2; ++nt)
                acc[mt][nt] = __builtin_amdgcn_mfma_f32_16x16x32_bf16(
                    af[mt], bfr[nt], acc[mt][nt], 0, 0, 0);
    };

    int nit = (t1 - t0) * 8;                       // 80 or 88
    stage(0); adv();                               // chunk 0 -> buf 0
    stage(1); adv();                               // chunk 1 -> buf 1
    int cur = 0;
    for (int i = 0; i < nit; ++i) {
        if (i + 1 < nit) asm volatile("s_waitcnt vmcnt(2)" ::: "memory");
        else             asm volatile("s_waitcnt vmcnt(0)" ::: "memory");
        __builtin_amdgcn_s_barrier();
        if (i + 2 < nit) { stage(cur == 0 ? 2 : cur - 1); adv(); }
        compute(cur);
        cur = (cur == 2) ? 0 : cur + 1;
    }

#pragma unroll
    for (int mt = 0; mt < 4; ++mt)
#pragma unroll
        for (int nt = 0; nt < 2; ++nt) {
            int col = nb + wc * 32 + nt * 16 + l15;
#pragma unroll
            for (int r = 0; r < 4; ++r) {
                int row = mb + wr * 64 + mt * 16 + l4 * 4 + r;
                atomicAdd(&h2f[(size_t)row * 256 + col], acc[mt][nt][r]);
            }
        }
}

// ---------------------------------------------------------------------------
// k_post = prep2 (blocks 0..5703) + caps2 (blocks 5704..5959), merged.
// Wdb2 layout [o][n][i][8] (per-WAVE coalesced in routing).
__global__ __launch_bounds__(256) void k_post(
        const void* __restrict__ wdig, const void* __restrict__ dw2,
        const void* __restrict__ dw3, const void* __restrict__ w1c,
        unsigned short* __restrict__ Wdb2,
        unsigned short* __restrict__ w2b,
        unsigned short* __restrict__ w3b,
        const float* __restrict__ h2f, const void* __restrict__ pb,
        unsigned short* __restrict__ caps) {
    __shared__ unsigned short wl[20480];           // 40KB; reused as f32[9216]
    int f = detect_f(w1c);
    int blk = blockIdx.x, tid = threadIdx.x;
    if (blk >= 5704) {                             // ---- caps2 branch ----
        float* ld = (float*)wl;                    // [pos 36][co 256], 36KB
        int b = blk - 5704;
#pragma unroll 4
        for (int p = 0; p < 36; ++p)
            ld[p * 256 + tid] = h2f[(size_t)b * 9216 + p * 256 + tid];
        __syncthreads();
        for (int c = tid; c < 1152; c += 256) {
            float h[8], ss = 0.f;
#pragma unroll
            for (int d = 0; d < 8; ++d) {
                int flat = c * 8 + d;              // = co*36 + pos
                int co = flat / 36, pos = flat - co * 36;
                float v = clampf(ld[pos * 256 + co] + rdf(pb, co, f), 20000.f);
                h[d] = v;
                ss += v * v;
            }
            float sc = sqrtf(ss) / (1.f + ss);
            u16x8 cv;
#pragma unroll
            for (int d = 0; d < 8; ++d) cv[d] = f2bf(h[d] * sc);
            *(u16x8*)(caps + ((size_t)b * 1152 + c) * 8) = cv;
        }
    } else if (blk < 72) {                         // ---- prep2: W_dig ----
        int i0 = blk * 16;
        size_t base = (size_t)i0 * 1280;
        for (int idx = tid; idx < 20480; idx += 256)
            wl[idx] = f2bf(rdf(wdig, base + idx, f));
        __syncthreads();
        if (tid < 160) {                           // (o,n) pair per thread
            int o = tid / 16, n = tid - o * 16;
            unsigned short* dst = Wdb2 + (size_t)o * 147456 + n * 9216 + i0 * 8;
            const unsigned short* src = wl + tid * 8;
#pragma unroll
            for (int i = 0; i < 16; ++i)
                *(uint4*)(dst + i * 8) = *(const uint4*)(src + i * 1280);
        }
    } else if (blk < 2120) {
        int idx = (blk - 72) * 256 + tid;          // 524,288
        w2b[idx] = f2bf(rdf(dw2, idx, f));
    } else {
        int idx = (blk - 2120) * 256 + tid;        // 917,504 (pad past 802,816)
        w3b[idx] = (idx < 802816) ? f2bf(rdf(dw3, idx, f)) : (unsigned short)0;
    }
}

// ---------------------------------------------------------------------------
// Dynamic routing + fused dec1.  One block per (o,b), o-major.  Round 1
// exact-uniform; rounds 2,3 no-max softmax (|a| bounded by squash norms).
__global__ __launch_bounds__(384) void k_routing(
        const unsigned short* __restrict__ caps, const unsigned short* __restrict__ Wdb2,
        const int* __restrict__ label, void* __restrict__ d_out,
        const void* __restrict__ dw1, const void* __restrict__ db1,
        unsigned short* __restrict__ r1b, const void* __restrict__ w1c) {
    int f = detect_f(w1c);
    int bid = blockIdx.x;
    int o = bid >> 8, b = bid & 255;               // 2560 = 10 o x 256 b
    int bo = b * 10 + o;                           // output index unchanged
    int tid = threadIdx.x;
    int wid = tid >> 6, lane = tid & 63;

    __shared__ float redw[6][16];
    __shared__ float sred[8];
    __shared__ float sbuf[16];
    __shared__ float vnl[16];

    float u[3][16];
    float a[3] = {0.f, 0.f, 0.f};
    const unsigned short* capb = caps + (size_t)b * 9216;
    const unsigned short* wob = Wdb2 + (size_t)o * 147456;

#pragma unroll
    for (int r = 0; r < 3; ++r) {
        int i = tid + r * 384;                       // covers 0..1151 exactly
        u16x8 cq = *(const u16x8*)(capb + i * 8);
        float cf[8];
#pragma unroll
        for (int d = 0; d < 8; ++d) cf[d] = bf2f(cq[d]);
#pragma unroll
        for (int n = 0; n < 16; ++n) {
            u16x8 q = *(const u16x8*)(wob + ((size_t)n * 1152 + i) * 8);
            float sacc = 0.f;
#pragma unroll
            for (int d = 0; d < 8; ++d) sacc += bf2f(q[d]) * cf[d];
            u[r][n] = sacc;
        }
    }

    // ---- Round 1: uniform coupling (exact) -----------------------------
    {
        float p[16];
#pragma unroll
        for (int n = 0; n < 16; ++n) p[n] = u[0][n] + u[1][n] + u[2][n];
#pragma unroll
        for (int off = 32; off; off >>= 1)
#pragma unroll
            for (int n = 0; n < 16; ++n) p[n] += __shfl_xor(p[n], off);
        if (lane == 0)
#pragma unroll
            for (int n = 0; n < 16; ++n) redw[wid][n] = p[n];
        __syncthreads();
        if (tid < 16) {
            float sn = 0.f;
#pragma unroll
            for (int w = 0; w < 6; ++w) sn += redw[w][tid];
            sbuf[tid] = sn * (1.f / 1152.f);
        }
        __syncthreads();
        float ss = 0.f;
#pragma unroll
        for (int n = 0; n < 16; ++n) ss += sbuf[n] * sbuf[n];
        float sc = sqrtf(ss) / (1.f + ss);
#pragma unroll
        for (int r = 0; r < 3; ++r) {
            float dot = 0.f;
#pragma unroll
            for (int n = 0; n < 16; ++n) dot += sbuf[n] * u[r][n];
            a[r] += sc * dot;
        }
    }

    // ---- Rounds 2,3: no-max softmax, fused es+p butterflies ------------
    for (int rr = 2; rr <= 3; ++rr) {
        float e[3], es = 0.f;
#pragma unroll
        for (int r = 0; r < 3; ++r) { e[r] = __expf(fminf(a[r], 70.f)); es += e[r]; }
        float p[16];
#pragma unroll
        for (int n = 0; n < 16; ++n)
            p[n] = e[0] * u[0][n] + e[1] * u[1][n] + e[2] * u[2][n];
#pragma unroll
        for (int off = 32; off; off >>= 1) {
            es += __shfl_xor(es, off);
#pragma unroll
            for (int n = 0; n < 16; ++n) p[n] += __shfl_xor(p[n], off);
        }
        if (lane == 0) {
#pragma unroll
            for (int n = 0; n < 16; ++n) redw[wid][n] = p[n];
            sred[wid] = es;
        }
        __syncthreads();
        if (tid < 16) {
            float S = 0.f, sn = 0.f;
#pragma unroll
            for (int w = 0; w < 6; ++w) { S += sred[w]; sn += redw[w][tid]; }
            sbuf[tid] = sn / S;
        }
        __syncthreads();
        float ss = 0.f;
#pragma unroll
        for (int n = 0; n < 16; ++n) ss += sbuf[n] * sbuf[n];
        float sc = sqrtf(ss) / (1.f + ss);

        if (rr < 3) {
#pragma unroll
            for (int r = 0; r < 3; ++r) {
                float dot = 0.f;
#pragma unroll
                for (int n = 0; n < 16; ++n) dot += sbuf[n] * u[r][n];
                a[r] += sc * dot;
            }
        } else {
            int lbl = label[b];
            if (tid < 16) {
                float vn = clampf(sbuf[tid] * sc, 1.f);
                if (f) ((float*)d_out)[(bo << 4) + tid] = vn;
                else   ((unsigned short*)d_out)[(bo << 4) + tid] = f2bf(vn);
                vnl[tid] = vn;
            }
            if (tid == 0) {
                float oh = (o == lbl) ? 1.f : 0.f;
                if (f) ((float*)d_out)[241664 + bo] = oh;
                else   ((unsigned short*)d_out)[241664 + bo] = f2bf(oh);
            }
            __syncthreads();                       // block-uniform path
            if (o == lbl) {                        // fused dec1
                for (int j = tid; j < 512; j += 384) {
                    float acc2 = rdf(db1, j, f);
                    size_t wb = (size_t)j * 160 + lbl * 16;
#pragma unroll
                    for (int n = 0; n < 16; ++n)
                        acc2 += rdf(dw1, wb + n, f) * vnl[n];
                    r1b[b * 512 + j] = f2bf(fmaxf(acc2, 0.f));
                }
            }
        }
    }
}

// ---------------------------------------------------------------------------
// decoder GEMM: C[256,N] = A[256,K] x B[N,K]^T (+bias, act). 128x128 tiles.
__global__ __launch_bounds__(256) void k_dgemm(
        const unsigned short* __restrict__ A, const unsigned short* __restrict__ B,
        const void* __restrict__ bias, int K, int mode, int nvalid, int ostride,
        unsigned short* __restrict__ outb, void* __restrict__ d_out,
        const void* __restrict__ w1c) {
    int f = detect_f(w1c);
    int tid = threadIdx.x;
    int wave = tid >> 6, lane = tid & 63;
    int wr = wave >> 1, wc = wave & 1;
    int mbase = blockIdx.x * 128 + wr * 64;
    int nbase = blockIdx.y * 128 + wc * 64;
    int l15 = lane & 15, l4 = lane >> 4;
    int koff = l4 * 8;

    f32x4 acc[4][4];
#pragma unroll
    for (int mt = 0; mt < 4; ++mt)
#pragma unroll
        for (int nt = 0; nt < 4; ++nt)
            acc[mt][nt] = (f32x4){0.f, 0.f, 0.f, 0.f};

    int nch = K >> 5;
    for (int kc = 0; kc < nch; ++kc) {
        int k0 = kc * 32 + koff;
        short8 af[4], bfr[4];
#pragma unroll
        for (int mt = 0; mt < 4; ++mt)
            af[mt] = *(const short8*)(A + (size_t)(mbase + mt * 16 + l15) * K + k0);
#pragma unroll
        for (int nt = 0; nt < 4; ++nt)
            bfr[nt] = *(const short8*)(B + (size_t)(nbase + nt * 16 + l15) * K + k0);
#pragma unroll
        for (int mt = 0; mt < 4; ++mt)
#pragma unroll
            for (int nt = 0; nt < 4; ++nt)
                acc[mt][nt] = __builtin_amdgcn_mfma_f32_16x16x32_bf16(
                    af[mt], bfr[nt], acc[mt][nt], 0, 0, 0);
    }

#pragma unroll
    for (int mt = 0; mt < 4; ++mt)
#pragma unroll
        for (int nt = 0; nt < 4; ++nt) {
            int col = nbase + nt * 16 + l15;
            float bv = (col < nvalid) ? rdf(bias, col, f) : 0.f;
#pragma unroll
            for (int r = 0; r < 4; ++r) {
                int row = mbase + mt * 16 + l4 * 4 + r;
                float v = acc[mt][nt][r] + bv;
                if (mode == 0) {
                    outb[(size_t)row * ostride + col] = f2bf(fmaxf(v, 0.f));
                } else if (col < nvalid) {
                    float a = clampf(v, 60.f);
                    float sig = 1.f / (1.f + __expf(-a));
                    size_t oi = 40960 + (size_t)row * 784 + col;
                    if (f) ((float*)d_out)[oi] = sig;
                    else   ((unsigned short*)d_out)[oi] = f2bf(sig);
                }
            }
        }
}

// ---------------------------------------------------------------------------
extern "C" void kernel_launch(void* const* d_in, const int* in_sizes, int n_in,
                              void* d_out, int out_size, void* d_ws, size_t ws_size,
                              hipStream_t stream) {
    const void* x    = d_in[0];
    const int*  lbl  = (const int*)d_in[1];
    const void* w1c  = d_in[2];
    const void* b1c  = d_in[3];
    const void* w2c  = d_in[4];
    const void* b2c  = d_in[5];
    const void* wdig = d_in[6];
    const void* dw1  = d_in[7];
    const void* db1  = d_in[8];
    const void* dw2  = d_in[9];
    const void* db2  = d_in[10];
    const void* dw3  = d_in[11];
    const void* db3  = d_in[12];
    (void)in_sizes; (void)n_in; (void)out_size; (void)ws_size;

    char* ws = (char*)d_ws;
    float* h2f           = (float*)(ws);                      // 9,437,184
    unsigned short* Bp3  = (unsigned short*)(ws + 9437184);   // 10,616,832 [dead after conv2]
    unsigned short* caps = (unsigned short*)(ws + 9437184);   //   overlay: 4,718,592
    unsigned short* B1p  = (unsigned short*)(ws + 20054016);  // 49,152
    unsigned short* h1p  = (unsigned short*)(ws + 20103168);  // 52,428,800 [dead after conv2]
    //   overlays inside h1p region (written after conv2 by k_post etc):
    unsigned short* Wdb2 = (unsigned short*)(ws + 20103168);  // 2,949,120
    unsigned short* w2b  = (unsigned short*)(ws + 23052288);  // 1,048,576
    unsigned short* w3b  = (unsigned short*)(ws + 24100864);  // 1,835,008
    unsigned short* r1b  = (unsigned short*)(ws + 25935872);  // 262,144
    unsigned short* r2b  = (unsigned short*)(ws + 26198016);  // 524,288

    hipLaunchKernelGGL(k_prep,  dim3(2656),     dim3(256), 0, stream, w1c, w2c, h2f, B1p, Bp3);
    hipLaunchKernelGGL(k_conv1, dim3(800, 2),   dim3(256), 0, stream, x, B1p, b1c, h1p, w1c);
    hipLaunchKernelGGL(k_conv2, dim3(72, 2, 8), dim3(512), 0, stream, h1p, Bp3, h2f);
    hipLaunchKernelGGL(k_post,  dim3(5960),     dim3(256), 0, stream,
                       wdig, dw2, dw3, w1c, Wdb2, w2b, w3b, h2f, b2c, caps);
    hipLaunchKernelGGL(k_routing, dim3(2560),   dim3(384), 0, stream, caps, Wdb2, lbl,
                       d_out, dw1, db1, r1b, w1c);
    hipLaunchKernelGGL(k_dgemm, dim3(2, 8),     dim3(256), 0, stream,
                       r1b, w2b, db2, 512, 0, 1024, 1024, r2b, d_out, w1c);
    hipLaunchKernelGGL(k_dgemm, dim3(2, 7),     dim3(256), 0, stream,
                       r2b, w3b, db3, 1024, 1, 784, 0, (unsigned short*)nullptr, d_out, w1c);
}